// Round 12
// baseline (261.197 us; speedup 1.0000x reference)
//
#include <hip/hip_runtime.h>
#include <hip/hip_bf16.h>

#define CDIM 128
#define LMAXC 512
#define QBLK 128
#define KVBLK 64

// 1/sqrt(128) * log2(e), folded into Wq/bq so softmax is exp2(s) directly
#define QSCALE (0.08838834764831845f * 1.4426950408889634f)

typedef __attribute__((ext_vector_type(8))) short bf16x8;
typedef __attribute__((ext_vector_type(4))) short bf16x4;
typedef __attribute__((ext_vector_type(4))) float f32x4;

__device__ inline short f2bf(float f) {
    union { float f; unsigned u; } v; v.f = f;
    unsigned r = v.u + 0x7FFFu + ((v.u >> 16) & 1u);
    return (short)(r >> 16);
}

__device__ inline bf16x8 cvt8v(float4 a, float4 b) {
    bf16x8 o;
    o[0] = f2bf(a.x); o[1] = f2bf(a.y); o[2] = f2bf(a.z); o[3] = f2bf(a.w);
    o[4] = f2bf(b.x); o[5] = f2bf(b.y); o[6] = f2bf(b.z); o[7] = f2bf(b.w);
    return o;
}

// attn-only packed convert (paired with LDS b64 packing; net win there)
__device__ inline unsigned pk2(float lo, float hi) {
    unsigned r;
    asm("v_cvt_pk_bf16_f32 %0, %1, %2" : "=v"(r) : "v"(lo), "v"(hi));
    return r;
}

__device__ inline void gload16(const void* g, void* l) {
    __builtin_amdgcn_global_load_lds(
        (const __attribute__((address_space(1))) unsigned*)g,
        (__attribute__((address_space(3))) unsigned*)l, 16, 0, 0);
}

__device__ inline void blk_barrier() {
    __builtin_amdgcn_sched_barrier(0);
    __builtin_amdgcn_s_barrier();
    __builtin_amdgcn_sched_barrier(0);
}

__device__ inline int pch(int q) { return ((q + (q >> 3)) & 7) << 4; }

// ---------------------------------------------------------------------------
// One-shot W conversion (Wq scaled by QSCALE).
// ---------------------------------------------------------------------------
__global__ void wcvt_kernel(const float* __restrict__ Wq,
                            const float* __restrict__ Wk,
                            const float* __restrict__ Wv,
                            short* __restrict__ Wbf)
{
    int t = blockIdx.x * 256 + threadIdx.x;
    int m = t / 2048;
    int e = (t % 2048) * 8;
    const float* W = (m == 0) ? Wq : (m == 1) ? Wk : Wv;
    float sc = (m == 0) ? QSCALE : 1.0f;
    float4 a = *reinterpret_cast<const float4*>(W + e);
    float4 b = *reinterpret_cast<const float4*>(W + e + 4);
    a.x *= sc; a.y *= sc; a.z *= sc; a.w *= sc;
    b.x *= sc; b.y *= sc; b.z *= sc; b.w *= sc;
    *reinterpret_cast<bf16x8*>(Wbf + m * 16384 + e) = cvt8v(a, b);
}

// ---------------------------------------------------------------------------
// Projection tile helpers (per-wave, 32 rows each).
// ---------------------------------------------------------------------------
// Q/K: swapped operands -> row-major out[token][d], 8B stores.
__device__ inline void tile_qk(const char* __restrict__ wlds,
                               const bf16x8 xfr[2][4],
                               const float* __restrict__ bias, float bsc,
                               short* __restrict__ outp, int rowb,
                               int lrow, int lhalf)
{
#pragma unroll
    for (int cf = 0; cf < 8; ++cf) {
        const int key = cf * 16 + lrow;
        bf16x8 wfr[4];
#pragma unroll
        for (int ks = 0; ks < 4; ++ks) {
            int wb = (key * 256 + (ks * 32 + lhalf * 8) * 2) ^ ((key & 7) << 4);
            wfr[ks] = *reinterpret_cast<const bf16x8*>(wlds + wb);
        }
        float4 bv4 = *reinterpret_cast<const float4*>(bias + cf * 16 + lhalf * 4);
#pragma unroll
        for (int xt = 0; xt < 2; ++xt) {
            f32x4 acc = {0.f, 0.f, 0.f, 0.f};
#pragma unroll
            for (int ks = 0; ks < 4; ++ks)
                acc = __builtin_amdgcn_mfma_f32_16x16x32_bf16(wfr[ks], xfr[xt][ks], acc, 0, 0, 0);
            bf16x4 pk;
            pk[0] = f2bf(acc[0] + bv4.x * bsc);
            pk[1] = f2bf(acc[1] + bv4.y * bsc);
            pk[2] = f2bf(acc[2] + bv4.z * bsc);
            pk[3] = f2bf(acc[3] + bv4.w * bsc);
            *reinterpret_cast<bf16x4*>(
                outp + (size_t)(rowb + xt * 16 + lrow) * CDIM
                     + cf * 16 + lhalf * 4) = pk;
        }
    }
}

// V: original operand order -> direct transposed stores Vt[d][token].
__device__ inline void tile_v(const char* __restrict__ wlds,
                              const bf16x8 xfr[2][4],
                              const float* __restrict__ bv,
                              short* __restrict__ Vt, int rowb, int N,
                              int lrow, int lhalf)
{
#pragma unroll
    for (int cf = 0; cf < 8; ++cf) {
        const int d = cf * 16 + lrow;
        bf16x8 wfr[4];
#pragma unroll
        for (int ks = 0; ks < 4; ++ks) {
            int wb = (d * 256 + (ks * 32 + lhalf * 8) * 2) ^ ((d & 7) << 4);
            wfr[ks] = *reinterpret_cast<const bf16x8*>(wlds + wb);
        }
        f32x4 acc0 = {0.f, 0.f, 0.f, 0.f};
        f32x4 acc1 = {0.f, 0.f, 0.f, 0.f};
#pragma unroll
        for (int ks = 0; ks < 4; ++ks) {
            acc0 = __builtin_amdgcn_mfma_f32_16x16x32_bf16(xfr[0][ks], wfr[ks], acc0, 0, 0, 0);
            acc1 = __builtin_amdgcn_mfma_f32_16x16x32_bf16(xfr[1][ks], wfr[ks], acc1, 0, 0, 0);
        }
        float bcol = bv[d];
        bf16x4 p0, p1;
#pragma unroll
        for (int r = 0; r < 4; ++r) {
            p0[r] = f2bf(acc0[r] + bcol);
            p1[r] = f2bf(acc1[r] + bcol);
        }
        short* vrow = Vt + (size_t)d * N + rowb + lhalf * 4;
        *reinterpret_cast<bf16x4*>(vrow)      = p0;   // tokens xt=0
        *reinterpret_cast<bf16x4*>(vrow + 16) = p1;   // tokens xt=1
    }
}

// ---------------------------------------------------------------------------
// Projection: grid (N/512, 3); 256-thread blocks, 32KB LDS (5 blocks/CU).
// Stage W once, then loop 4 row-tiles of 128 with NO barriers inside --
// waves drift out of phase so loads of one wave overlap compute of others
// (R7-R11 were barrier-phase-locked: all waves load together then go
// memory-silent; BW stuck at 2.4 TB/s = ~35% duty cycle).
// ---------------------------------------------------------------------------
__global__ __launch_bounds__(256) void proj_kernel(
    const float* __restrict__ Qf, const float* __restrict__ Kf,
    const short* __restrict__ Wbf,
    const float* __restrict__ bq, const float* __restrict__ bk,
    const float* __restrict__ bv,
    short* __restrict__ Qp, short* __restrict__ Kp, short* __restrict__ Vt,
    int N)
{
    __shared__ __align__(16) char wlds[32768];   // 128 rows x 256B, swizzled

    const int tid   = threadIdx.x;
    const int lane  = tid & 63;
    const int wv    = tid >> 6;                  // 0..3
    const int lrow  = lane & 15;
    const int lhalf = lane >> 4;
    const int row0  = blockIdx.x * 512;
    const int which = blockIdx.y;                // 0=Q, 1=K, 2=V
    const float* X  = (which == 0) ? Qf : Kf;
    const short* Wg = Wbf + which * 16384;

    // ---- stage W -> LDS (pre-swizzled source, linear dest), once ----
#pragma unroll
    for (int j = 0; j < 8; ++j) {
        int beta = j * 4096 + tid * 16;
        int r  = beta >> 8;
        int gs = ((beta >> 4) & 15) ^ (r & 7);
        gload16(Wg + r * 128 + gs * 8, wlds + beta);
    }
    __syncthreads();   // drains W gload_lds; last barrier in the kernel

    // ---- 4 tiles of 128 rows, barrier-free loop ----
    for (int t = 0; t < 4; ++t) {
        const int rowb = row0 + t * 128 + wv * 32;

        bf16x8 xfr[2][4];
#pragma unroll
        for (int xt = 0; xt < 2; ++xt) {
            const float* xr = X + (size_t)(rowb + xt * 16 + lrow) * CDIM + lhalf * 8;
#pragma unroll
            for (int ks = 0; ks < 4; ++ks) {
                const float4* s = reinterpret_cast<const float4*>(xr + ks * 32);
                xfr[xt][ks] = cvt8v(s[0], s[1]);
            }
        }

        if (which == 0)
            tile_qk(wlds, xfr, bq, QSCALE, Qp, rowb, lrow, lhalf);
        else if (which == 1)
            tile_qk(wlds, xfr, bk, 1.0f, Kp, rowb, lrow, lhalf);
        else
            tile_v(wlds, xfr, bv, Vt, rowb, N, lrow, lhalf);
    }
}

// ---------------------------------------------------------------------------
// Flash attention: double-buffered global_load_lds staging, counted vmcnt,
// raw s_barrier, swapped QK^T, packed P via cvt_pk, flat exp2 softmax.
// LDS: 2 x (K 16KB + Vt 16KB) + P 16KB = 80KB -> 2 blocks/CU.
// ---------------------------------------------------------------------------
__global__ __launch_bounds__(256) void attn_kernel(
    const short* __restrict__ Qp, const short* __restrict__ Kp,
    const short* __restrict__ VtG, const int* __restrict__ offset,
    float* __restrict__ out, int Ntot)
{
    __shared__ __align__(16) char smem[81920];
    char* lds_p = smem + 65536;

    // XCD-clustered mapping: all q-blocks of a segment on one XCD
    const int nq = LMAXC / QBLK;                 // 4
    int flat = blockIdx.x, total = gridDim.x;
    int seg, qb;
    if ((total & (8 * nq - 1)) == 0) {
        int per = total >> 3;                    // blocks per XCD
        int xcd = flat & 7;
        int wi  = flat >> 3;
        int sl  = wi / nq;
        qb  = wi - sl * nq;
        seg = xcd * (per / nq) + sl;
    } else { seg = flat / nq; qb = flat - seg * nq; }

    const int start = (seg == 0) ? 0 : offset[seg - 1];
    int len = offset[seg] - start;
    if (len > LMAXC) len = LMAXC;
    const int q0 = qb * QBLK;
    if (q0 >= len) return;

    const int tid   = threadIdx.x;
    const int lane  = tid & 63;
    const int wv    = tid >> 6;
    const int lrow  = lane & 15;
    const int lhalf = lane >> 4;
    const int ntiles = (len + KVBLK - 1) / KVBLK;
    const int lm1 = len - 1;

    // stage one K/Vt tile into buffer bb (8 gload_lds per wave)
    auto stage = [&](int kv0, int bb) {
        char* kb = smem + bb * 32768;
        char* vb = kb + 16384;
#pragma unroll
        for (int j = 0; j < 4; ++j) {
            int beta = j * 4096 + wv * 1024 + (lane << 4);
            // K: rows of 256B, inverse-swizzled source granule
            int r  = beta >> 8;
            int gs = ((beta >> 4) & 15) ^ (r & 7);
            int rg = kv0 + r; if (rg > lm1) rg = lm1;
            gload16(Kp + (((size_t)(start + rg)) << 7) + (gs << 3),
                    kb + j * 4096 + wv * 1024);
            // Vt: rows of 128B
            int d   = beta >> 7;
            int gs2 = ((beta >> 4) & 7) ^ (d & 7);
            long gk = (long)start + kv0 + (gs2 << 3);
            if (gk + 8 > Ntot) gk = Ntot - 8;
            gload16(VtG + (size_t)d * Ntot + gk,
                    vb + j * 4096 + wv * 1024);
        }
    };

    stage(0, 0);

    // Q fragments (2 q-tiles of 16 rows; wave owns 32 q rows)
    bf16x8 aq[2][4];
#pragma unroll
    for (int qt = 0; qt < 2; ++qt) {
        int qr = q0 + wv * 32 + qt * 16 + lrow;
        if (qr > lm1) qr = lm1;
        const short* qrow = Qp + (size_t)(start + qr) * CDIM;
#pragma unroll
        for (int ks = 0; ks < 4; ++ks)
            aq[qt][ks] = *reinterpret_cast<const bf16x8*>(qrow + ks * 32 + lhalf * 8);
    }

    f32x4 acc_o[2][8];
    float lsum[2] = {0.f, 0.f};
#pragma unroll
    for (int qt = 0; qt < 2; ++qt)
#pragma unroll
        for (int df = 0; df < 8; ++df) acc_o[qt][df] = (f32x4){0.f, 0.f, 0.f, 0.f};

    const int wbase = wv * 4096;

    for (int t = 0; t < ntiles; ++t) {
        const int kv0 = t * KVBLK;
        const int bb  = t & 1;
        if (t + 1 < ntiles) {
            stage(kv0 + KVBLK, bb ^ 1);
            asm volatile("s_waitcnt vmcnt(8)" ::: "memory");
        } else {
            asm volatile("s_waitcnt vmcnt(0)" ::: "memory");
        }
        blk_barrier();

        char* lds_k  = smem + bb * 32768;
        char* lds_vt = lds_k + 16384;
        const bool tail = (kv0 + KVBLK > len);

        // ---- S^T = K Q^T (swapped): lane holds q=lrow, keys kf*16+lhalf*4+r
        f32x4 s0[4], s1[4];
        __builtin_amdgcn_s_setprio(1);
#pragma unroll
        for (int kf = 0; kf < 4; ++kf) {
            s0[kf] = (f32x4){0.f, 0.f, 0.f, 0.f};
            s1[kf] = (f32x4){0.f, 0.f, 0.f, 0.f};
            int key = kf * 16 + lrow;
#pragma unroll
            for (int ks = 0; ks < 4; ++ks) {
                int kbo = (key * 256 + (ks * 32 + lhalf * 8) * 2) ^ ((key & 7) << 4);
                bf16x8 kfr = *reinterpret_cast<const bf16x8*>(lds_k + kbo);
                s0[kf] = __builtin_amdgcn_mfma_f32_16x16x32_bf16(kfr, aq[0][ks], s0[kf], 0, 0, 0);
                s1[kf] = __builtin_amdgcn_mfma_f32_16x16x32_bf16(kfr, aq[1][ks], s1[kf], 0, 0, 0);
            }
        }
        __builtin_amdgcn_s_setprio(0);

        // ---- flat softmax + packed P writes (keys contiguous per lane)
        const int keyb0 = kv0 + lhalf * 4;
#pragma unroll
        for (int qt = 0; qt < 2; ++qt) {
            const int qlocal = qt * 16 + lrow;
            const int rowoff = wbase + qlocal * 128;
            const int swz = pch(qlocal);
#pragma unroll
            for (int kf = 0; kf < 4; ++kf) {
                f32x4 sv = qt ? s1[kf] : s0[kf];
                float p[4];
#pragma unroll
                for (int r = 0; r < 4; ++r) {
                    float pv = exp2f(sv[r]);
                    if (tail && (keyb0 + kf * 16 + r >= len)) pv = 0.f;
                    p[r] = pv;
                    lsum[qt] += pv;
                }
                unsigned long long w =
                    (unsigned long long)pk2(p[0], p[1]) |
                    ((unsigned long long)pk2(p[2], p[3]) << 32);
                *reinterpret_cast<unsigned long long*>(
                    lds_p + rowoff + ((kf * 32 + lhalf * 8) ^ swz)) = w;
            }
        }

        // ---- O += P V  (per-wave P region, no barrier needed)
        __builtin_amdgcn_s_setprio(1);
#pragma unroll
        for (int ks2 = 0; ks2 < 2; ++ks2) {
            bf16x8 ap0 = *reinterpret_cast<const bf16x8*>(
                lds_p + wbase + lrow * 128 + ((ks2 * 64 + lhalf * 16) ^ pch(lrow)));
            bf16x8 ap1 = *reinterpret_cast<const bf16x8*>(
                lds_p + wbase + (16 + lrow) * 128 + ((ks2 * 64 + lhalf * 16) ^ pch(16 + lrow)));
            int k0 = ks2 * 32 + lhalf * 8;
#pragma unroll
            for (int df = 0; df < 8; ++df) {
                int d = df * 16 + lrow;
                int vb2 = (d * 128 + k0 * 2) ^ ((d & 7) << 4);
                bf16x8 bvf = *reinterpret_cast<const bf16x8*>(lds_vt + vb2);
                acc_o[0][df] = __builtin_amdgcn_mfma_f32_16x16x32_bf16(ap0, bvf, acc_o[0][df], 0, 0, 0);
                acc_o[1][df] = __builtin_amdgcn_mfma_f32_16x16x32_bf16(ap1, bvf, acc_o[1][df], 0, 0, 0);
            }
        }
        __builtin_amdgcn_s_setprio(0);

        blk_barrier();
    }

    // ---- epilogue: reduce l across the 4-lane group, redistribute, store
#pragma unroll
    for (int qt = 0; qt < 2; ++qt) {
        float l = lsum[qt];
        l += __shfl_xor(l, 16);
        l += __shfl_xor(l, 32);          // lane now has full sum for q=lrow
        float rinv[4];
#pragma unroll
        for (int r = 0; r < 4; ++r)
            rinv[r] = 1.0f / __shfl(l, lhalf * 4 + r);
#pragma unroll
        for (int df = 0; df < 8; ++df)
#pragma unroll
            for (int r = 0; r < 4; ++r) {
                int qg = q0 + wv * 32 + qt * 16 + lhalf * 4 + r;
                if (qg < len)
                    out[(size_t)(start + qg) * CDIM + df * 16 + lrow]
                        = acc_o[qt][df][r] * rinv[r];
            }
    }
}

extern "C" void kernel_launch(void* const* d_in, const int* in_sizes, int n_in,
                              void* d_out, int out_size, void* d_ws, size_t ws_size,
                              hipStream_t stream) {
    const float* Qf = (const float*)d_in[0];
    const float* Kf = (const float*)d_in[1];
    const float* Wq = (const float*)d_in[2];
    const float* bq = (const float*)d_in[3];
    const float* Wk = (const float*)d_in[4];
    const float* bk = (const float*)d_in[5];
    const float* Wv = (const float*)d_in[6];
    const float* bv_ = (const float*)d_in[7];
    const int* offset = (const int*)d_in[8];

    const int N = in_sizes[0] / CDIM;     // 262144
    const int B = in_sizes[8];            // 512

    short* Qp = (short*)d_ws;
    short* Kp = Qp + (size_t)N * CDIM;
    short* Vt = Kp + (size_t)N * CDIM;    // [C][N]
    float* out = (float*)d_out;

    size_t base_need = (size_t)3 * N * CDIM * 2;
    short* Wbf = (ws_size >= base_need + 3 * 16384 * 2)
               ? (Vt + (size_t)N * CDIM) : (short*)d_out;

    wcvt_kernel<<<24, 256, 0, stream>>>(Wq, Wk, Wv, Wbf);

    dim3 pgrid(N / 512, 3);
    proj_kernel<<<pgrid, 256, 0, stream>>>(Qf, Kf, Wbf, bq, bk, bv_,
                                           Qp, Kp, Vt, N);

    attn_kernel<<<dim3(B * (LMAXC / QBLK)), 256, 0, stream>>>(
        Qp, Kp, Vt, offset, out, N);
}

// Round 13
// 234.616 us; speedup vs baseline: 1.1133x; 1.1133x over previous
//
#include <hip/hip_runtime.h>
#include <hip/hip_bf16.h>

#define CDIM 128
#define LMAXC 512
#define QBLK 128
#define KVBLK 64

// 1/sqrt(128) * log2(e), folded into Wq/bq so softmax is exp2(s) directly
#define QSCALE (0.08838834764831845f * 1.4426950408889634f)

typedef __attribute__((ext_vector_type(8))) short bf16x8;
typedef __attribute__((ext_vector_type(4))) short bf16x4;
typedef __attribute__((ext_vector_type(4))) float f32x4;

__device__ inline short f2bf(float f) {
    union { float f; unsigned u; } v; v.f = f;
    unsigned r = v.u + 0x7FFFu + ((v.u >> 16) & 1u);
    return (short)(r >> 16);
}

__device__ inline bf16x8 cvt8v(float4 a, float4 b) {
    bf16x8 o;
    o[0] = f2bf(a.x); o[1] = f2bf(a.y); o[2] = f2bf(a.z); o[3] = f2bf(a.w);
    o[4] = f2bf(b.x); o[5] = f2bf(b.y); o[6] = f2bf(b.z); o[7] = f2bf(b.w);
    return o;
}

// attn-only packed convert (paired with LDS b64 packing; net win there)
__device__ inline unsigned pk2(float lo, float hi) {
    unsigned r;
    asm("v_cvt_pk_bf16_f32 %0, %1, %2" : "=v"(r) : "v"(lo), "v"(hi));
    return r;
}

__device__ inline void gload16(const void* g, void* l) {
    __builtin_amdgcn_global_load_lds(
        (const __attribute__((address_space(1))) unsigned*)g,
        (__attribute__((address_space(3))) unsigned*)l, 16, 0, 0);
}

__device__ inline void blk_barrier() {
    __builtin_amdgcn_sched_barrier(0);
    __builtin_amdgcn_s_barrier();
    __builtin_amdgcn_sched_barrier(0);
}

__device__ inline int pch(int q) { return ((q + (q >> 3)) & 7) << 4; }

// ---------------------------------------------------------------------------
// One-shot W conversion (Wq scaled by QSCALE).
// ---------------------------------------------------------------------------
__global__ void wcvt_kernel(const float* __restrict__ Wq,
                            const float* __restrict__ Wk,
                            const float* __restrict__ Wv,
                            short* __restrict__ Wbf)
{
    int t = blockIdx.x * 256 + threadIdx.x;
    int m = t / 2048;
    int e = (t % 2048) * 8;
    const float* W = (m == 0) ? Wq : (m == 1) ? Wk : Wv;
    float sc = (m == 0) ? QSCALE : 1.0f;
    float4 a = *reinterpret_cast<const float4*>(W + e);
    float4 b = *reinterpret_cast<const float4*>(W + e + 4);
    a.x *= sc; a.y *= sc; a.z *= sc; a.w *= sc;
    b.x *= sc; b.y *= sc; b.z *= sc; b.w *= sc;
    *reinterpret_cast<bf16x8*>(Wbf + m * 16384 + e) = cvt8v(a, b);
}

// ---------------------------------------------------------------------------
// Projection tile helpers (per-wave, 32 rows each).
// ---------------------------------------------------------------------------
// K: swapped operands -> row-major out[token][d], 8B stores.
__device__ inline void tile_qk(const char* __restrict__ wlds,
                               const bf16x8 xfr[2][4],
                               const float* __restrict__ bias, float bsc,
                               short* __restrict__ outp, int rowb,
                               int lrow, int lhalf)
{
#pragma unroll
    for (int cf = 0; cf < 8; ++cf) {
        const int key = cf * 16 + lrow;
        bf16x8 wfr[4];
#pragma unroll
        for (int ks = 0; ks < 4; ++ks) {
            int wb = (key * 256 + (ks * 32 + lhalf * 8) * 2) ^ ((key & 7) << 4);
            wfr[ks] = *reinterpret_cast<const bf16x8*>(wlds + wb);
        }
        float4 bv4 = *reinterpret_cast<const float4*>(bias + cf * 16 + lhalf * 4);
#pragma unroll
        for (int xt = 0; xt < 2; ++xt) {
            f32x4 acc = {0.f, 0.f, 0.f, 0.f};
#pragma unroll
            for (int ks = 0; ks < 4; ++ks)
                acc = __builtin_amdgcn_mfma_f32_16x16x32_bf16(wfr[ks], xfr[xt][ks], acc, 0, 0, 0);
            bf16x4 pk;
            pk[0] = f2bf(acc[0] + bv4.x * bsc);
            pk[1] = f2bf(acc[1] + bv4.y * bsc);
            pk[2] = f2bf(acc[2] + bv4.z * bsc);
            pk[3] = f2bf(acc[3] + bv4.w * bsc);
            *reinterpret_cast<bf16x4*>(
                outp + (size_t)(rowb + xt * 16 + lrow) * CDIM
                     + cf * 16 + lhalf * 4) = pk;
        }
    }
}

// V: original operand order -> direct transposed stores Vt[d][token].
__device__ inline void tile_v(const char* __restrict__ wlds,
                              const bf16x8 xfr[2][4],
                              const float* __restrict__ bv,
                              short* __restrict__ Vt, int rowb, int N,
                              int lrow, int lhalf)
{
#pragma unroll
    for (int cf = 0; cf < 8; ++cf) {
        const int d = cf * 16 + lrow;
        bf16x8 wfr[4];
#pragma unroll
        for (int ks = 0; ks < 4; ++ks) {
            int wb = (d * 256 + (ks * 32 + lhalf * 8) * 2) ^ ((d & 7) << 4);
            wfr[ks] = *reinterpret_cast<const bf16x8*>(wlds + wb);
        }
        f32x4 acc0 = {0.f, 0.f, 0.f, 0.f};
        f32x4 acc1 = {0.f, 0.f, 0.f, 0.f};
#pragma unroll
        for (int ks = 0; ks < 4; ++ks) {
            acc0 = __builtin_amdgcn_mfma_f32_16x16x32_bf16(xfr[0][ks], wfr[ks], acc0, 0, 0, 0);
            acc1 = __builtin_amdgcn_mfma_f32_16x16x32_bf16(xfr[1][ks], wfr[ks], acc1, 0, 0, 0);
        }
        float bcol = bv[d];
        bf16x4 p0, p1;
#pragma unroll
        for (int r = 0; r < 4; ++r) {
            p0[r] = f2bf(acc0[r] + bcol);
            p1[r] = f2bf(acc1[r] + bcol);
        }
        short* vrow = Vt + (size_t)d * N + rowb + lhalf * 4;
        *reinterpret_cast<bf16x4*>(vrow)      = p0;   // tokens xt=0
        *reinterpret_cast<bf16x4*>(vrow + 16) = p1;   // tokens xt=1
    }
}

// ---------------------------------------------------------------------------
// K+V projection only (Q is fused into attn). 512-thread blocks, 256 rows.
// Stage Wk, shared X frags, K pass; re-stage Wv; V pass (R11's proven path).
// ---------------------------------------------------------------------------
__global__ __launch_bounds__(512) void projkv_kernel(
    const float* __restrict__ Kf, const short* __restrict__ Wbf,
    const float* __restrict__ bk, const float* __restrict__ bv,
    short* __restrict__ Kp, short* __restrict__ Vt, int N)
{
    __shared__ __align__(16) char wlds[32768];   // 128 rows x 256B, swizzled

    const int tid   = threadIdx.x;
    const int lane  = tid & 63;
    const int wv    = tid >> 6;                  // 0..7
    const int lrow  = lane & 15;
    const int lhalf = lane >> 4;
    const int rowb  = blockIdx.x * 256 + wv * 32;

    // ---- stage Wk -> LDS (pre-swizzled source, linear dest) ----
#pragma unroll
    for (int j = 0; j < 4; ++j) {
        int beta = j * 8192 + tid * 16;
        int r  = beta >> 8;
        int gs = ((beta >> 4) & 15) ^ (r & 7);
        gload16(Wbf + 16384 + r * 128 + gs * 8, wlds + beta);
    }

    // ---- X fragments (one 32-row strip per wave, kept for both passes) ----
    bf16x8 xfr[2][4];
#pragma unroll
    for (int xt = 0; xt < 2; ++xt) {
        const float* xr = Kf + (size_t)(rowb + xt * 16 + lrow) * CDIM + lhalf * 8;
#pragma unroll
        for (int ks = 0; ks < 4; ++ks) {
            const float4* s = reinterpret_cast<const float4*>(xr + ks * 32);
            xfr[xt][ks] = cvt8v(s[0], s[1]);
        }
    }
    __syncthreads();   // drains Wk gload_lds

    tile_qk(wlds, xfr, bk, 1.0f, Kp, rowb, lrow, lhalf);
    __syncthreads();                          // all waves done reading Wk
#pragma unroll
    for (int j = 0; j < 4; ++j) {             // re-stage Wv over Wk
        int beta = j * 8192 + tid * 16;
        int r  = beta >> 8;
        int gs = ((beta >> 4) & 15) ^ (r & 7);
        gload16(Wbf + 32768 + r * 128 + gs * 8, wlds + beta);
    }
    __syncthreads();                          // drain Wv staging
    tile_v(wlds, xfr, bv, Vt, rowb, N, lrow, lhalf);
}

// ---------------------------------------------------------------------------
// Flash attention with FUSED Q-projection prologue. Per wave: project its 32
// q rows (mfma(Wq,Xq), proj's exact math), bounce through buffer-1 LDS to
// re-layout into B-operand fragments (write = proj store pattern, read = old
// Qp load pattern), all per-wave private. Then the proven pipeline loop.
// LDS: 2 x (K 16KB + Vt 16KB) + P 16KB = 80KB -> 2 blocks/CU.
// ---------------------------------------------------------------------------
__global__ __launch_bounds__(256) void attn_kernel(
    const float* __restrict__ Qf, const short* __restrict__ Wbf,
    const float* __restrict__ bq,
    const short* __restrict__ Kp, const short* __restrict__ VtG,
    const int* __restrict__ offset, float* __restrict__ out, int Ntot)
{
    __shared__ __align__(16) char smem[81920];
    char* lds_p = smem + 65536;

    // XCD-clustered mapping: all q-blocks of a segment on one XCD
    const int nq = LMAXC / QBLK;                 // 4
    int flat = blockIdx.x, total = gridDim.x;
    int seg, qb;
    if ((total & (8 * nq - 1)) == 0) {
        int per = total >> 3;                    // blocks per XCD
        int xcd = flat & 7;
        int wi  = flat >> 3;
        int sl  = wi / nq;
        qb  = wi - sl * nq;
        seg = xcd * (per / nq) + sl;
    } else { seg = flat / nq; qb = flat - seg * nq; }

    const int start = (seg == 0) ? 0 : offset[seg - 1];
    int len = offset[seg] - start;
    if (len > LMAXC) len = LMAXC;
    const int q0 = qb * QBLK;
    if (q0 >= len) return;

    const int tid   = threadIdx.x;
    const int lane  = tid & 63;
    const int wv    = tid >> 6;
    const int lrow  = lane & 15;
    const int lhalf = lane >> 4;
    const int ntiles = (len + KVBLK - 1) / KVBLK;
    const int lm1 = len - 1;

    // ---- Q-projection prologue (per-wave private; uses buffer-1 LDS) ----
    bf16x8 aq[2][4];
    {
        char* qstage = smem + 32768 + wv * 8192;   // [32 q rows][256B] swizzled

        bf16x8 xq[2][4];
#pragma unroll
        for (int qt = 0; qt < 2; ++qt) {
            int qr = q0 + wv * 32 + qt * 16 + lrow;
            if (qr > lm1) qr = lm1;
            const float* xr = Qf + (size_t)(start + qr) * CDIM + lhalf * 8;
#pragma unroll
            for (int ks = 0; ks < 4; ++ks) {
                const float4* s = reinterpret_cast<const float4*>(xr + ks * 32);
                xq[qt][ks] = cvt8v(s[0], s[1]);
            }
        }
#pragma unroll
        for (int cf = 0; cf < 8; ++cf) {
            const int key = cf * 16 + lrow;
            bf16x8 wfr[4];
#pragma unroll
            for (int ks = 0; ks < 4; ++ks)
                wfr[ks] = *reinterpret_cast<const bf16x8*>(
                    Wbf + key * CDIM + ks * 32 + lhalf * 8);
            float4 bq4 = *reinterpret_cast<const float4*>(bq + cf * 16 + lhalf * 4);
#pragma unroll
            for (int qt = 0; qt < 2; ++qt) {
                f32x4 acc = {0.f, 0.f, 0.f, 0.f};
#pragma unroll
                for (int ks = 0; ks < 4; ++ks)
                    acc = __builtin_amdgcn_mfma_f32_16x16x32_bf16(wfr[ks], xq[qt][ks], acc, 0, 0, 0);
                bf16x4 pk;
                pk[0] = f2bf(acc[0] + bq4.x * QSCALE);
                pk[1] = f2bf(acc[1] + bq4.y * QSCALE);
                pk[2] = f2bf(acc[2] + bq4.z * QSCALE);
                pk[3] = f2bf(acc[3] + bq4.w * QSCALE);
                int ql = qt * 16 + lrow;           // token = D col = lane&15
                *reinterpret_cast<bf16x4*>(
                    qstage + ql * 256 + ((cf * 32 + lhalf * 8) ^ pch(ql))) = pk;
            }
        }
        asm volatile("s_waitcnt lgkmcnt(0)" ::: "memory");
#pragma unroll
        for (int qt = 0; qt < 2; ++qt) {
            int ql = qt * 16 + lrow;
#pragma unroll
            for (int ks = 0; ks < 4; ++ks)
                aq[qt][ks] = *reinterpret_cast<const bf16x8*>(
                    qstage + ql * 256 + ((ks * 64 + lhalf * 16) ^ pch(ql)));
        }
    }
    __syncthreads();   // all waves done with buffer-1 before staging reuses it

    // stage one K/Vt tile into buffer bb (8 gload_lds per wave)
    auto stage = [&](int kv0, int bb) {
        char* kb = smem + bb * 32768;
        char* vb = kb + 16384;
#pragma unroll
        for (int j = 0; j < 4; ++j) {
            int beta = j * 4096 + wv * 1024 + (lane << 4);
            // K: rows of 256B, inverse-swizzled source granule
            int r  = beta >> 8;
            int gs = ((beta >> 4) & 15) ^ (r & 7);
            int rg = kv0 + r; if (rg > lm1) rg = lm1;
            gload16(Kp + (((size_t)(start + rg)) << 7) + (gs << 3),
                    kb + j * 4096 + wv * 1024);
            // Vt: rows of 128B
            int d   = beta >> 7;
            int gs2 = ((beta >> 4) & 7) ^ (d & 7);
            long gk = (long)start + kv0 + (gs2 << 3);
            if (gk + 8 > Ntot) gk = Ntot - 8;
            gload16(VtG + (size_t)d * Ntot + gk,
                    vb + j * 4096 + wv * 1024);
        }
    };

    stage(0, 0);

    f32x4 acc_o[2][8];
    float lsum[2] = {0.f, 0.f};
#pragma unroll
    for (int qt = 0; qt < 2; ++qt)
#pragma unroll
        for (int df = 0; df < 8; ++df) acc_o[qt][df] = (f32x4){0.f, 0.f, 0.f, 0.f};

    const int wbase = wv * 4096;

    for (int t = 0; t < ntiles; ++t) {
        const int kv0 = t * KVBLK;
        const int bb  = t & 1;
        if (t + 1 < ntiles) {
            stage(kv0 + KVBLK, bb ^ 1);
            asm volatile("s_waitcnt vmcnt(8)" ::: "memory");
        } else {
            asm volatile("s_waitcnt vmcnt(0)" ::: "memory");
        }
        blk_barrier();

        char* lds_k  = smem + bb * 32768;
        char* lds_vt = lds_k + 16384;
        const bool tail = (kv0 + KVBLK > len);

        // ---- S^T = K Q^T (swapped): lane holds q=lrow, keys kf*16+lhalf*4+r
        f32x4 s0[4], s1[4];
        __builtin_amdgcn_s_setprio(1);
#pragma unroll
        for (int kf = 0; kf < 4; ++kf) {
            s0[kf] = (f32x4){0.f, 0.f, 0.f, 0.f};
            s1[kf] = (f32x4){0.f, 0.f, 0.f, 0.f};
            int key = kf * 16 + lrow;
#pragma unroll
            for (int ks = 0; ks < 4; ++ks) {
                int kbo = (key * 256 + (ks * 32 + lhalf * 8) * 2) ^ ((key & 7) << 4);
                bf16x8 kfr = *reinterpret_cast<const bf16x8*>(lds_k + kbo);
                s0[kf] = __builtin_amdgcn_mfma_f32_16x16x32_bf16(kfr, aq[0][ks], s0[kf], 0, 0, 0);
                s1[kf] = __builtin_amdgcn_mfma_f32_16x16x32_bf16(kfr, aq[1][ks], s1[kf], 0, 0, 0);
            }
        }
        __builtin_amdgcn_s_setprio(0);

        // ---- flat softmax + packed P writes (keys contiguous per lane)
        const int keyb0 = kv0 + lhalf * 4;
#pragma unroll
        for (int qt = 0; qt < 2; ++qt) {
            const int qlocal = qt * 16 + lrow;
            const int rowoff = wbase + qlocal * 128;
            const int swz = pch(qlocal);
#pragma unroll
            for (int kf = 0; kf < 4; ++kf) {
                f32x4 sv = qt ? s1[kf] : s0[kf];
                float p[4];
#pragma unroll
                for (int r = 0; r < 4; ++r) {
                    float pv = exp2f(sv[r]);
                    if (tail && (keyb0 + kf * 16 + r >= len)) pv = 0.f;
                    p[r] = pv;
                    lsum[qt] += pv;
                }
                unsigned long long w =
                    (unsigned long long)pk2(p[0], p[1]) |
                    ((unsigned long long)pk2(p[2], p[3]) << 32);
                *reinterpret_cast<unsigned long long*>(
                    lds_p + rowoff + ((kf * 32 + lhalf * 8) ^ swz)) = w;
            }
        }

        // ---- O += P V  (per-wave P region, no barrier needed)
        __builtin_amdgcn_s_setprio(1);
#pragma unroll
        for (int ks2 = 0; ks2 < 2; ++ks2) {
            bf16x8 ap0 = *reinterpret_cast<const bf16x8*>(
                lds_p + wbase + lrow * 128 + ((ks2 * 64 + lhalf * 16) ^ pch(lrow)));
            bf16x8 ap1 = *reinterpret_cast<const bf16x8*>(
                lds_p + wbase + (16 + lrow) * 128 + ((ks2 * 64 + lhalf * 16) ^ pch(16 + lrow)));
            int k0 = ks2 * 32 + lhalf * 8;
#pragma unroll
            for (int df = 0; df < 8; ++df) {
                int d = df * 16 + lrow;
                int vb2 = (d * 128 + k0 * 2) ^ ((d & 7) << 4);
                bf16x8 bvf = *reinterpret_cast<const bf16x8*>(lds_vt + vb2);
                acc_o[0][df] = __builtin_amdgcn_mfma_f32_16x16x32_bf16(ap0, bvf, acc_o[0][df], 0, 0, 0);
                acc_o[1][df] = __builtin_amdgcn_mfma_f32_16x16x32_bf16(ap1, bvf, acc_o[1][df], 0, 0, 0);
            }
        }
        __builtin_amdgcn_s_setprio(0);

        blk_barrier();
    }

    // ---- epilogue: reduce l across the 4-lane group, redistribute, store
#pragma unroll
    for (int qt = 0; qt < 2; ++qt) {
        float l = lsum[qt];
        l += __shfl_xor(l, 16);
        l += __shfl_xor(l, 32);          // lane now has full sum for q=lrow
        float rinv[4];
#pragma unroll
        for (int r = 0; r < 4; ++r)
            rinv[r] = 1.0f / __shfl(l, lhalf * 4 + r);
#pragma unroll
        for (int df = 0; df < 8; ++df)
#pragma unroll
            for (int r = 0; r < 4; ++r) {
                int qg = q0 + wv * 32 + qt * 16 + lhalf * 4 + r;
                if (qg < len)
                    out[(size_t)(start + qg) * CDIM + df * 16 + lrow]
                        = acc_o[qt][df][r] * rinv[r];
            }
    }
}

extern "C" void kernel_launch(void* const* d_in, const int* in_sizes, int n_in,
                              void* d_out, int out_size, void* d_ws, size_t ws_size,
                              hipStream_t stream) {
    const float* Qf = (const float*)d_in[0];
    const float* Kf = (const float*)d_in[1];
    const float* Wq = (const float*)d_in[2];
    const float* bq = (const float*)d_in[3];
    const float* Wk = (const float*)d_in[4];
    const float* bk = (const float*)d_in[5];
    const float* Wv = (const float*)d_in[6];
    const float* bv_ = (const float*)d_in[7];
    const int* offset = (const int*)d_in[8];

    const int N = in_sizes[0] / CDIM;     // 262144
    const int B = in_sizes[8];            // 512

    short* Wbf = (short*)d_ws;            // 3 x 128 x 128 bf16 (96KB)
    short* Kp  = Wbf + 3 * 16384;
    short* Vt  = Kp + (size_t)N * CDIM;   // [C][N]
    float* out = (float*)d_out;

    wcvt_kernel<<<24, 256, 0, stream>>>(Wq, Wk, Wv, Wbf);

    projkv_kernel<<<dim3(N / 256), 512, 0, stream>>>(Kf, Wbf, bk, bv_,
                                                     Kp, Vt, N);

    attn_kernel<<<dim3(B * (LMAXC / QBLK)), 256, 0, stream>>>(
        Qf, Wbf, bq, Kp, Vt, offset, out, N);
}